// Round 6
// baseline (174.863 us; speedup 1.0000x reference)
//
#include <hip/hip_runtime.h>
#include <hip/hip_bf16.h>

// Problem constants (fixed by reference)
constexpr int kN = 32768;
constexpr int kC = 1000;
constexpr int NB_A = 2048;        // probs blocks: 4 waves x 4 rows (16-lane groups) = 16 rows
constexpr int NB_B = 1024;        // y blocks: 4 waves x 8 rows
constexpr int NB1 = NB_A + NB_B;
constexpr int NB3 = 512;          // histogram blocks

// ---------------------------------------------------------------------------
// K1: block-specialized; last block (device ticket) performs the former K2.
//  probs blocks: wave processes 4 rows via 16-lane groups. Row = 16 steps of
//    256B (float4/lane), static 2-deep ping-pong -> continuous load stream,
//    compile-time load offsets, one 4-round width-16 butterfly per 4 rows.
//  y blocks: early-exit one-hot scan (R3 form), gather p[lbl], w[lbl].
// ---------------------------------------------------------------------------
__global__ __launch_bounds__(256) void k1_main(
    const float* __restrict__ probs, const float* __restrict__ y,
    const float* __restrict__ wts, float* __restrict__ unc,
    int* __restrict__ pred, float* __restrict__ partMM /* NB_A*2 */,
    float* __restrict__ partCF /* NB_B*2 */, float* __restrict__ scal,
    int* __restrict__ ticket) {
  const int lane = threadIdx.x & 63;
  const int wid = threadIdx.x >> 6;
  __shared__ float sA[4], sB[4];
  __shared__ int sLast;

  if (blockIdx.x < NB_A) {
    // ---------------- probs pass: entropy + argmax + min/max ----------------
    const int sl = lane & 15;                    // sub-lane within 16-group
    const int g = lane >> 4;                     // group = which row
    const int row = blockIdx.x * 16 + wid * 4 + g;
    const float* pr = probs + (size_t)row * kC;

    float ent = 0.f, bv = -3.4e38f; int bi = 0;
    float4 buf[2];                               // static after full unroll
    buf[0] = *reinterpret_cast<const float4*>(pr + sl * 4);  // step 0 (always in-bounds)
#pragma unroll
    for (int s = 0; s < 16; ++s) {
      if (s + 1 < 16) {                          // prefetch next step
        const int c0n = (s + 1) * 64 + sl * 4;
        buf[(s + 1) & 1] = (c0n < kC)
            ? *reinterpret_cast<const float4*>(pr + c0n)
            : make_float4(0.f, 0.f, 0.f, 0.f);
      }
      const float4 p4 = buf[s & 1];
      const int c0 = s * 64 + sl * 4;
#pragma unroll
      for (int j = 0; j < 4; ++j) {
        const float p = (&p4.x)[j];
        ent += p * __logf(fmaxf(p, 1e-10f));     // pad p=0 contributes 0
        if (p > bv) { bv = p; bi = c0 + j; }     // ascending index in lane
      }
    }
    // 4-round butterfly within each 16-lane group (first-index tie-break)
#pragma unroll
    for (int off = 1; off < 16; off <<= 1) {
      ent += __shfl_xor(ent, off, 16);
      const float bv2 = __shfl_xor(bv, off, 16);
      const int bi2 = __shfl_xor(bi, off, 16);
      if (bv2 > bv || (bv2 == bv && bi2 < bi)) { bv = bv2; bi = bi2; }
    }
    const float u = -ent;
    if (sl == 0) { unc[row] = u; pred[row] = bi; }
    // wave min/max across the 4 groups, then block partial
    float mn = u, mx = u;
    mn = fminf(mn, __shfl_xor(mn, 16)); mx = fmaxf(mx, __shfl_xor(mx, 16));
    mn = fminf(mn, __shfl_xor(mn, 32)); mx = fmaxf(mx, __shfl_xor(mx, 32));
    if (lane == 0) { sA[wid] = mn; sB[wid] = mx; }
    __syncthreads();
    if (threadIdx.x == 0) {
      float a = 3.4e38f, b = -3.4e38f;
#pragma unroll
      for (int q = 0; q < 4; ++q) { a = fminf(a, sA[q]); b = fmaxf(b, sB[q]); }
      partMM[blockIdx.x * 2 + 0] = a;
      partMM[blockIdx.x * 2 + 1] = b;
    }
  } else {
    // ---------------- y pass: early-exit label scan + CE/focal -------------
    const int gwb = (blockIdx.x - NB_A) * 4 + wid;  // 0..4095
    constexpr float kLogClip8 = -18.420680743952367f;  // log(1e-8)
    float ce = 0.f, fo = 0.f;
#pragma unroll 1
    for (int r = 0; r < 8; ++r) {                 // 8 rows per wave
      const int i = gwb + r * 4096;
      const float* yr = y + (size_t)i * kC;
      int lbl = -1;
#pragma unroll 1
      for (int step = 0; step < 4; ++step) {      // early-exit scan
        const int c0 = step * 256 + lane * 4;
        float4 y4 = make_float4(0.f, 0.f, 0.f, 0.f);
        if (c0 < kC) y4 = *reinterpret_cast<const float4*>(yr + c0);
        int loc = -1;
#pragma unroll
        for (int j = 0; j < 4; ++j) if ((&y4.x)[j] != 0.0f) loc = j;
        if (__any(loc >= 0)) {                    // wave-uniform break
          if (loc >= 0) lbl = c0 + loc;
          break;
        }
      }
      if (lbl >= 0) {                             // exactly one lane per row
        const float p = probs[(size_t)i * kC + lbl];
        const float w = wts[(size_t)i * kC + lbl];
        const float lp = fmaxf(__logf(fmaxf(p, 1e-10f)), kLogClip8);
        ce += lp;
        fo += lp * w * (1.0f - p);
      }
    }
#pragma unroll
    for (int off = 32; off; off >>= 1) {
      ce += __shfl_xor(ce, off);
      fo += __shfl_xor(fo, off);
    }
    if (lane == 0) { sA[wid] = ce; sB[wid] = fo; }
    __syncthreads();
    if (threadIdx.x == 0) {
      float c = 0.f, f = 0.f;
#pragma unroll
      for (int q = 0; q < 4; ++q) { c += sA[q]; f += sB[q]; }
      const int bb = blockIdx.x - NB_A;
      partCF[bb * 2 + 0] = c;
      partCF[bb * 2 + 1] = f;
    }
  }

  // ---------------- ticket: last block performs the former K2 --------------
  __syncthreads();                     // all block stores drained (vmcnt(0) at barrier)
  if (threadIdx.x == 0) {
    __threadfence();                   // release: partials visible device-wide
    sLast = (atomicAdd(ticket, 1) == NB1 - 1) ? 1 : 0;
  }
  __syncthreads();
  if (!sLast) return;
  __threadfence();                     // acquire: all other blocks' partials

  const int t = threadIdx.x;
  float mn = 3.4e38f, mx = -3.4e38f, c = 0.f, f = 0.f;
  for (int b = t; b < NB_A; b += 256) {
    mn = fminf(mn, partMM[b * 2 + 0]);
    mx = fmaxf(mx, partMM[b * 2 + 1]);
  }
  for (int b = t; b < NB_B; b += 256) {
    c += partCF[b * 2 + 0];
    f += partCF[b * 2 + 1];
  }
  __shared__ float sc[256], sf[256], smn[256], smx[256];
  sc[t] = c; sf[t] = f; smn[t] = mn; smx[t] = mx;
  __syncthreads();
  for (int off = 128; off; off >>= 1) {
    if (t < off) {
      sc[t] += sc[t + off]; sf[t] += sf[t + off];
      smn[t] = fminf(smn[t], smn[t + off]);
      smx[t] = fmaxf(smx[t], smx[t + off]);
    }
    __syncthreads();
  }
  // flat argmax of y == argmax of row 0 (first 1.0 in flattened array)
  float bv = -3.4e38f; int bi = 0;
  for (int c0 = t; c0 < kC; c0 += 256) {
    const float v = y[c0];
    if (v > bv) { bv = v; bi = c0; }
  }
  __shared__ float sbv[256]; __shared__ int sbi[256];
  sbv[t] = bv; sbi[t] = bi;
  __syncthreads();
  for (int off = 128; off; off >>= 1) {
    if (t < off) {
      if (sbv[t + off] > sbv[t] ||
          (sbv[t + off] == sbv[t] && sbi[t + off] < sbi[t])) {
        sbv[t] = sbv[t + off]; sbi[t] = sbi[t + off];
      }
    }
    __syncthreads();
  }
  if (t == 0) {
    scal[0] = -sc[0] / (float)kN;        // ce_mean
    scal[1] = -sf[0] / (float)kN;        // focal_mean
    const float umin = smn[0], umax = smx[0];
    scal[2] = umin; scal[3] = umax;
    for (int k = 0; k < 21; ++k) {
      const float th = (float)((double)k * 0.05);  // linspace(0,1,21) in f32
      scal[4 + k] = umin + th * (umax - umin);
    }
    reinterpret_cast<int*>(scal)[25] = sbi[0];
  }
}

// ---------------------------------------------------------------------------
// K3: histogram of cert_w / uncw by k0 = #{unc_th < unc}, split by acc.
// Bins: [0..21]=certw&acc [22..43]=uncw&acc [44..65]=certw&!acc [66..87]=uncw&!acc
// Last block (device ticket) performs the former K4 final reduce.
// ---------------------------------------------------------------------------
__global__ __launch_bounds__(64) void k3_hist(
    const float* __restrict__ unc, const int* __restrict__ pred,
    const float* __restrict__ scal, float* __restrict__ part3 /* NB3*88 */,
    float* __restrict__ out, int* __restrict__ ticket) {
  __shared__ float hist[88 * 64];
  __shared__ float th[21];
  __shared__ int s_label, sLast;
  const int t = threadIdx.x;
  for (int b = 0; b < 88; ++b) hist[b * 64 + t] = 0.f;
  if (t < 21) th[t] = scal[4 + t];
  if (t == 0) s_label = reinterpret_cast<const int*>(scal)[25];
  __syncthreads();
  const float entmax = logf(1000.0f);
  const int label = s_label;

  for (int i = blockIdx.x * 64 + t; i < kN; i += NB3 * 64) {
    const float u = unc[i];
    const bool acc = (pred[i] == label);
    const float e = u / entmax;
    const float num = e * 0.9f;                       // e*(1-THETA)
    const float den = fmaxf((1.0f - e) * 0.1f, 1e-10f);
    const float v = 100.0f * logf(fmaxf(num / den, 1e-10f));
    const float s = 1.0f / (1.0f + expf(-v));         // sigmoid
    const float tt = tanhf(u);
    const float cw = (1.0f - s) * (1.0f - tt);
    const float uw = s * tt;
    int k0 = 0;
#pragma unroll
    for (int k = 0; k < 21; ++k) k0 += (th[k] < u) ? 1 : 0;
    const int base = acc ? 0 : 44;
    hist[(base + k0) * 64 + t] += cw;
    hist[(base + 22 + k0) * 64 + t] += uw;
  }
  __syncthreads();
  for (int b = t; b < 88; b += 64) {
    float s2 = 0.f;
    for (int q = 0; q < 64; ++q) s2 += hist[b * 64 + q];
    part3[blockIdx.x * 88 + b] = s2;
  }

  // ---------------- ticket: last block performs the former K4 --------------
  __syncthreads();                     // part3 stores drained
  if (t == 0) {
    __threadfence();
    sLast = (atomicAdd(ticket, 1) == NB3 - 1) ? 1 : 0;
  }
  __syncthreads();
  if (!sLast) return;
  __threadfence();

  __shared__ float h[88];
  for (int b = t; b < 88; b += 64) {   // coalesced across t per q-step
    float s2 = 0.f;
    for (int q = 0; q < NB3; ++q) s2 += part3[q * 88 + b];
    h[b] = s2;
  }
  __syncthreads();
  if (t == 0) {
    float totAU = 0.f, totIU = 0.f;
    for (int k = 0; k < 22; ++k) { totAU += h[22 + k]; totIU += h[66 + k]; }
    float avu[21];
    float cAC = 0.f, cAU = 0.f, cIC = 0.f, cIU = 0.f;
    for (int k = 0; k < 21; ++k) {
      cAC += h[k]; cAU += h[22 + k]; cIC += h[44 + k]; cIU += h[66 + k];
      const float n_ac = cAC;
      const float n_au = totAU - cAU;
      const float n_ic = cIC;
      const float n_iu = totIU - cIU;
      avu[k] = (n_ac + n_iu) / (n_ac + n_au + n_ic + n_iu + 1e-10f);
    }
    float auc = 0.f;
    for (int k = 0; k < 20; ++k) {
      const float th0 = (float)((double)k * 0.05);
      const float th1 = (float)((double)(k + 1) * 0.05);
      auc += 0.5f * (avu[k + 1] + avu[k]) * (th1 - th0);
    }
    out[0] = -__logf(fmaxf(auc, 1e-10f)) + scal[1];  // savu_loss (BETA=1)
    out[1] = scal[0];                                // ce_loss
  }
}

extern "C" void kernel_launch(void* const* d_in, const int* in_sizes, int n_in,
                              void* d_out, int out_size, void* d_ws, size_t ws_size,
                              hipStream_t stream) {
  const float* probs = (const float*)d_in[0];
  const float* y     = (const float*)d_in[1];
  const float* wts   = (const float*)d_in[2];
  float* out = (float*)d_out;

  float* ws     = (float*)d_ws;
  float* unc    = ws;                        // kN floats
  int*   pred   = (int*)(ws + kN);           // kN ints
  float* partMM = ws + 2 * kN;               // NB_A*2 floats
  float* partCF = partMM + NB_A * 2;         // NB_B*2 floats
  float* scal   = partCF + NB_B * 2;         // 32 floats
  float* part3  = scal + 32;                 // NB3*88 floats
  int*   tickets = (int*)(part3 + NB3 * 88); // 2 ints

  hipMemsetAsync(tickets, 0, 2 * sizeof(int), stream);  // reset per launch
  k1_main<<<dim3(NB1), dim3(256), 0, stream>>>(
      probs, y, wts, unc, pred, partMM, partCF, scal, &tickets[0]);
  k3_hist<<<dim3(NB3), dim3(64), 0, stream>>>(
      unc, pred, scal, part3, out, &tickets[1]);
}

// Round 7
// 65.622 us; speedup vs baseline: 2.6647x; 2.6647x over previous
//
#include <hip/hip_runtime.h>
#include <hip/hip_bf16.h>

// Problem constants (fixed by reference)
constexpr int kN = 32768;
constexpr int kC = 1000;
constexpr int NB_A = 2048;        // probs-pass blocks (4 waves) -> 8192 waves -> 4 rows/wave
constexpr int NB_B = 1024;        // y-pass blocks (4 waves) -> 4096 waves -> 8 rows/wave
constexpr int NB3 = 512;          // histogram blocks

// ---------------------------------------------------------------------------
// K1: block-specialized (R3 structure; logf -> __logf is the only change).
//  Blocks [0,NB_A): stream probs -> entropy, argmax, umin/umax.
//  Blocks [NB_A,NB_A+NB_B): early-exit one-hot scan of y, then gather
//    p[lbl], w[lbl] for CE/focal.
// ---------------------------------------------------------------------------
__global__ __launch_bounds__(256) void k1_main(
    const float* __restrict__ probs, const float* __restrict__ y,
    const float* __restrict__ wts, float* __restrict__ unc,
    int* __restrict__ pred, float* __restrict__ partMM /* NB_A*2 */,
    float* __restrict__ partCF /* NB_B*2 */) {
  const int lane = threadIdx.x & 63;
  const int wid = threadIdx.x >> 6;

  if (blockIdx.x < NB_A) {
    // ---------------- probs pass: entropy + argmax + min/max ----------------
    const int gw = blockIdx.x * 4 + wid;          // 0..8191
    float mn = 3.4e38f, mx = -3.4e38f;
#pragma unroll 1
    for (int r = 0; r < 4; ++r) {                 // 4 rows per wave
      const int i = gw + r * 8192;
      const float* pr = probs + (size_t)i * kC;
      float4 p4[4];
#pragma unroll
      for (int k = 0; k < 4; ++k) {
        const int c0 = k * 256 + lane * 4;
        if (c0 < kC) p4[k] = *reinterpret_cast<const float4*>(pr + c0);
        else p4[k] = make_float4(0.f, 0.f, 0.f, 0.f);
      }
      float ent = 0.f, bv = -3.4e38f; int bi = 0;
#pragma unroll
      for (int k = 0; k < 4; ++k) {
        const int c0 = k * 256 + lane * 4;
#pragma unroll
        for (int j = 0; j < 4; ++j) {
          const float p = (&p4[k].x)[j];
          ent += p * __logf(fmaxf(p, 1e-10f));    // v_log_f32; pad p=0 -> 0
          if (p > bv) { bv = p; bi = c0 + j; }
        }
      }
#pragma unroll
      for (int off = 32; off; off >>= 1) {
        ent += __shfl_xor(ent, off);
        const float bv2 = __shfl_xor(bv, off);
        const int bi2 = __shfl_xor(bi, off);
        if (bv2 > bv || (bv2 == bv && bi2 < bi)) { bv = bv2; bi = bi2; }
      }
      const float u = -ent;
      if (lane == 0) { unc[i] = u; pred[i] = bi; }
      mn = fminf(mn, u); mx = fmaxf(mx, u);
    }
    __shared__ float sMin[4], sMax[4];
    if (lane == 0) { sMin[wid] = mn; sMax[wid] = mx; }
    __syncthreads();
    if (threadIdx.x == 0) {
      float a = 3.4e38f, b = -3.4e38f;
#pragma unroll
      for (int q = 0; q < 4; ++q) { a = fminf(a, sMin[q]); b = fmaxf(b, sMax[q]); }
      partMM[blockIdx.x * 2 + 0] = a;
      partMM[blockIdx.x * 2 + 1] = b;
    }
  } else {
    // ---------------- y pass: early-exit label scan + CE/focal -------------
    const int gwb = (blockIdx.x - NB_A) * 4 + wid;  // 0..4095
    constexpr float kLogClip8 = -18.420680743952367f;  // log(1e-8)
    float ce = 0.f, fo = 0.f;
#pragma unroll 1
    for (int r = 0; r < 8; ++r) {                 // 8 rows per wave
      const int i = gwb + r * 4096;
      const float* yr = y + (size_t)i * kC;
      int lbl = -1;
#pragma unroll 1
      for (int step = 0; step < 4; ++step) {      // early-exit scan
        const int c0 = step * 256 + lane * 4;
        float4 y4 = make_float4(0.f, 0.f, 0.f, 0.f);
        if (c0 < kC) y4 = *reinterpret_cast<const float4*>(yr + c0);
        int loc = -1;
#pragma unroll
        for (int j = 0; j < 4; ++j) if ((&y4.x)[j] != 0.0f) loc = j;
        if (__any(loc >= 0)) {                    // wave-uniform break
          if (loc >= 0) lbl = c0 + loc;
          break;
        }
      }
      if (lbl >= 0) {                             // exactly one lane per row
        const float p = probs[(size_t)i * kC + lbl];
        const float w = wts[(size_t)i * kC + lbl];
        const float lp = fmaxf(__logf(fmaxf(p, 1e-10f)), kLogClip8);
        ce += lp;
        fo += lp * w * (1.0f - p);
      }
    }
#pragma unroll
    for (int off = 32; off; off >>= 1) {
      ce += __shfl_xor(ce, off);
      fo += __shfl_xor(fo, off);
    }
    __shared__ float sCe[4], sFo[4];
    if (lane == 0) { sCe[wid] = ce; sFo[wid] = fo; }
    __syncthreads();
    if (threadIdx.x == 0) {
      float c = 0.f, f = 0.f;
#pragma unroll
      for (int q = 0; q < 4; ++q) { c += sCe[q]; f += sFo[q]; }
      const int bb = blockIdx.x - NB_A;
      partCF[bb * 2 + 0] = c;
      partCF[bb * 2 + 1] = f;
    }
  }
}

// ---------------------------------------------------------------------------
// K2: reduce partials; flat argmax of y (row 0, first-index tie-break);
// compute unc_th[21].
// scal layout: [0]=ce_mean [1]=focal_mean [2]=umin [3]=umax [4..24]=unc_th
//              [25]=labels (int bits)
// ---------------------------------------------------------------------------
__global__ __launch_bounds__(256) void k2_scalars(
    const float* __restrict__ y, const float* __restrict__ partMM,
    const float* __restrict__ partCF, float* __restrict__ scal) {
  const int t = threadIdx.x;
  float mn = 3.4e38f, mx = -3.4e38f, c = 0.f, f = 0.f;
  for (int b = t; b < NB_A; b += 256) {
    mn = fminf(mn, partMM[b * 2 + 0]);
    mx = fmaxf(mx, partMM[b * 2 + 1]);
  }
  for (int b = t; b < NB_B; b += 256) {
    c += partCF[b * 2 + 0];
    f += partCF[b * 2 + 1];
  }
  __shared__ float sc[256], sf[256], smn[256], smx[256];
  sc[t] = c; sf[t] = f; smn[t] = mn; smx[t] = mx;
  __syncthreads();
  for (int off = 128; off; off >>= 1) {
    if (t < off) {
      sc[t] += sc[t + off]; sf[t] += sf[t + off];
      smn[t] = fminf(smn[t], smn[t + off]);
      smx[t] = fmaxf(smx[t], smx[t + off]);
    }
    __syncthreads();
  }
  // flat argmax of y == argmax of row 0 (first 1.0 in flattened array)
  float bv = -3.4e38f; int bi = 0;
  for (int c0 = t; c0 < kC; c0 += 256) {
    const float v = y[c0];
    if (v > bv) { bv = v; bi = c0; }
  }
  __shared__ float sbv[256]; __shared__ int sbi[256];
  sbv[t] = bv; sbi[t] = bi;
  __syncthreads();
  for (int off = 128; off; off >>= 1) {
    if (t < off) {
      if (sbv[t + off] > sbv[t] ||
          (sbv[t + off] == sbv[t] && sbi[t + off] < sbi[t])) {
        sbv[t] = sbv[t + off]; sbi[t] = sbi[t + off];
      }
    }
    __syncthreads();
  }
  if (t == 0) {
    scal[0] = -sc[0] / (float)kN;        // ce_mean
    scal[1] = -sf[0] / (float)kN;        // focal_mean
    const float umin = smn[0], umax = smx[0];
    scal[2] = umin; scal[3] = umax;
    for (int k = 0; k < 21; ++k) {
      const float th = (float)((double)k * 0.05);  // linspace(0,1,21) in f32
      scal[4 + k] = umin + th * (umax - umin);
    }
    reinterpret_cast<int*>(scal)[25] = sbi[0];
  }
}

// ---------------------------------------------------------------------------
// K3: histogram of cert_w / uncw by k0 = #{unc_th < unc}, split by acc.
// Bins: [0..21]=certw&acc [22..43]=uncw&acc [44..65]=certw&!acc [66..87]=uncw&!acc
// ---------------------------------------------------------------------------
__global__ __launch_bounds__(64) void k3_hist(
    const float* __restrict__ unc, const int* __restrict__ pred,
    const float* __restrict__ scal, float* __restrict__ part3 /* NB3*88 */) {
  __shared__ float hist[88 * 64];
  __shared__ float th[21];
  __shared__ int s_label;
  const int t = threadIdx.x;
  for (int b = 0; b < 88; ++b) hist[b * 64 + t] = 0.f;
  if (t < 21) th[t] = scal[4 + t];
  if (t == 0) s_label = reinterpret_cast<const int*>(scal)[25];
  __syncthreads();
  const float entmax = logf(1000.0f);
  const int label = s_label;

  for (int i = blockIdx.x * 64 + t; i < kN; i += NB3 * 64) {
    const float u = unc[i];
    const bool acc = (pred[i] == label);
    const float e = u / entmax;
    const float num = e * 0.9f;                       // e*(1-THETA)
    const float den = fmaxf((1.0f - e) * 0.1f, 1e-10f);
    const float v = 100.0f * logf(fmaxf(num / den, 1e-10f));
    const float s = 1.0f / (1.0f + expf(-v));         // sigmoid
    const float tt = tanhf(u);
    const float cw = (1.0f - s) * (1.0f - tt);
    const float uw = s * tt;
    int k0 = 0;
#pragma unroll
    for (int k = 0; k < 21; ++k) k0 += (th[k] < u) ? 1 : 0;
    const int base = acc ? 0 : 44;
    hist[(base + k0) * 64 + t] += cw;
    hist[(base + 22 + k0) * 64 + t] += uw;
  }
  __syncthreads();
  for (int b = t; b < 88; b += 64) {
    float s2 = 0.f;
    for (int q = 0; q < 64; ++q) s2 += hist[b * 64 + q];
    part3[blockIdx.x * 88 + b] = s2;
  }
}

// ---------------------------------------------------------------------------
// K4: final reduce over NB3 partials, cumsums -> avu -> trapezoid -> outputs.
// ---------------------------------------------------------------------------
__global__ __launch_bounds__(128) void k4_final(
    const float* __restrict__ part3, const float* __restrict__ scal,
    float* __restrict__ out) {
  __shared__ float h[88];
  const int t = threadIdx.x;
  for (int b = t; b < 88; b += 128) {
    float s = 0.f;
    for (int q = 0; q < NB3; ++q) s += part3[q * 88 + b];
    h[b] = s;
  }
  __syncthreads();
  if (t == 0) {
    float totAU = 0.f, totIU = 0.f;
    for (int k = 0; k < 22; ++k) { totAU += h[22 + k]; totIU += h[66 + k]; }
    float avu[21];
    float cAC = 0.f, cAU = 0.f, cIC = 0.f, cIU = 0.f;
    for (int k = 0; k < 21; ++k) {
      cAC += h[k]; cAU += h[22 + k]; cIC += h[44 + k]; cIU += h[66 + k];
      const float n_ac = cAC;
      const float n_au = totAU - cAU;
      const float n_ic = cIC;
      const float n_iu = totIU - cIU;
      avu[k] = (n_ac + n_iu) / (n_ac + n_au + n_ic + n_iu + 1e-10f);
    }
    float auc = 0.f;
    for (int k = 0; k < 20; ++k) {
      const float th0 = (float)((double)k * 0.05);
      const float th1 = (float)((double)(k + 1) * 0.05);
      auc += 0.5f * (avu[k + 1] + avu[k]) * (th1 - th0);
    }
    out[0] = -logf(fmaxf(auc, 1e-10f)) + scal[1];  // savu_loss (BETA=1)
    out[1] = scal[0];                              // ce_loss
  }
}

extern "C" void kernel_launch(void* const* d_in, const int* in_sizes, int n_in,
                              void* d_out, int out_size, void* d_ws, size_t ws_size,
                              hipStream_t stream) {
  const float* probs = (const float*)d_in[0];
  const float* y     = (const float*)d_in[1];
  const float* wts   = (const float*)d_in[2];
  float* out = (float*)d_out;

  float* ws     = (float*)d_ws;
  float* unc    = ws;                        // kN floats
  int*   pred   = (int*)(ws + kN);           // kN ints
  float* partMM = ws + 2 * kN;               // NB_A*2 floats
  float* partCF = partMM + NB_A * 2;         // NB_B*2 floats
  float* scal   = partCF + NB_B * 2;         // 32 floats
  float* part3  = scal + 32;                 // NB3*88 floats

  k1_main<<<dim3(NB_A + NB_B), dim3(256), 0, stream>>>(
      probs, y, wts, unc, pred, partMM, partCF);
  k2_scalars<<<dim3(1), dim3(256), 0, stream>>>(y, partMM, partCF, scal);
  k3_hist<<<dim3(NB3), dim3(64), 0, stream>>>(unc, pred, scal, part3);
  k4_final<<<dim3(1), dim3(128), 0, stream>>>(part3, scal, out);
}